// Round 4
// baseline (144.314 us; speedup 1.0000x reference)
//
#include <hip/hip_runtime.h>
#include <hip/hip_bf16.h>
#include <stdint.h>

// Problem constants (fixed by reference)
#define N_IMG   16
#define C_IN    256
#define H_IN    32
#define W_IN    32
#define OH      30
#define OW      30
#define K_SEL   1152                   // C*KH*KW/2
#define OUTC    512
#define RY_TOT  (N_IMG * OH)           // 480 (n,y) rows
#define M_HAT   (RY_TOT * 32)          // 15360 = padded M (ow 30 -> 32)
#define X_ELEMS (N_IMG * C_IN * H_IN * W_IN)   // 4194304
#define OUT_SP  (OH * OW)              // 900
#define CHW     (C_IN * H_IN * W_IN)   // 262144

#define TO      256                    // o-tile (2x R3: 16 MFMA/wave-iter, halves x re-gather)
#define TM      64                     // m-tile = 2 ry rows x 32 xw
#define NMT     (M_HAT / TM)           // 240
#define NOT     (OUTC / TO)            // 2
#define BSTR    40                     // Bs row stride (shorts): 80B rows, 16B-aligned b128
#define KITER   (K_SEL / 32)           // 36

typedef float f32x4  __attribute__((ext_vector_type(4)));
typedef short bf16x8 __attribute__((ext_vector_type(8)));   // 8 bf16 = 4 VGPRs

__device__ __forceinline__ unsigned short f2bf(float f) {   // fp32 -> bf16 RNE
    unsigned int u = __float_as_uint(f);
    u += 0x7FFFu + ((u >> 16) & 1u);
    return (unsigned short)(u >> 16);
}

// async global->LDS, 16B/lane; LDS dst wave-uniform base, HW adds lane*16.
__device__ __forceinline__ void gl_lds16(const void* g, void* lds) {
    __builtin_amdgcn_global_load_lds(
        (const __attribute__((address_space(1))) unsigned int*)g,
        (__attribute__((address_space(3))) unsigned int*)lds,
        16, 0, 0);
}

// ---------------------------------------------------------------------------
// Prep: koff decode + coalesced LDS-tile transpose w(K_SEL x OUTC fp32) ->
// wT(OUTC x K_SEL bf16). Grid (36 s-tiles, 16 o-tiles) x 256 thr.
// ---------------------------------------------------------------------------
__global__ void prep_kernel(const int* __restrict__ idx, const float* __restrict__ w,
                            int* __restrict__ koff, unsigned short* __restrict__ wT) {
    __shared__ float tile[32][33];                 // +1 pad: phase1 conflict-free
    const int bx = blockIdx.x, by = blockIdx.y, t = threadIdx.x;

    if (by == 0) {                                 // fold koff decode into first row
        int k = bx * 256 + t;
        if (k < K_SEL) {
            int v = idx[k];
            int c = v / 9, rem = v - c * 9;
            int i = rem / 3, j = rem - i * 3;
            koff[k] = c * (H_IN * W_IN) + i * W_IN + j;
        }
    }
    const int s0 = bx * 32, o0 = by * 32;
    const int oc = t & 31, sg = t >> 5;
#pragma unroll
    for (int i = 0; i < 4; ++i) {                  // coalesced 128B reads along o
        int sl = sg * 4 + i;
        tile[sl][oc] = w[(s0 + sl) * OUTC + o0 + oc];
    }
    __syncthreads();
    const int ol = t >> 3, sq = t & 7;             // write along s: coalesced
    unsigned int u0 = (unsigned int)f2bf(tile[sq * 4 + 0][ol]) |
                      ((unsigned int)f2bf(tile[sq * 4 + 1][ol]) << 16);
    unsigned int u1 = (unsigned int)f2bf(tile[sq * 4 + 2][ol]) |
                      ((unsigned int)f2bf(tile[sq * 4 + 3][ol]) << 16);
    uint2 pk; pk.x = u0; pk.y = u1;
    *reinterpret_cast<uint2*>(&wT[(size_t)(o0 + ol) * K_SEL + s0 + sq * 4]) = pk;
}

// ---------------------------------------------------------------------------
// Fused GEMM: out[n,o,y,x] = sum_k wT[o][k] * x[n, koff[k] + y*32 + xw]
// Tile 256o x 64m, BK=32, 480 blocks. 16 MFMA per wave-iter (m97 ratio);
// B staged straight from x (int4 koS read, packed cvt, ds_write_b64);
// A via 4x global_load_lds. x-gather software-pipelined 1 iter ahead.
// o-siblings are bid and bid+240 (240%8==0 -> same XCD -> x L2 reuse).
// ---------------------------------------------------------------------------
__global__ __launch_bounds__(256, 2)
void gemm_kernel(const unsigned short* __restrict__ wT, const float* __restrict__ x,
                 const int* __restrict__ koff, float* __restrict__ out) {
    __shared__ __align__(16) unsigned short As[TO * 32];    // rows = o-local, k-contig (16KB)
    __shared__ __align__(16) unsigned short Bs[TM * BSTR];  // rows = m-local, padded (5KB)
    __shared__ __align__(16) int koS[K_SEL];

    const int t    = threadIdx.x;
    const int wave = t >> 6;
    const int lane = t & 63;
    const int quad = lane >> 4;
    const int lo   = lane & 15;

    const int bid = blockIdx.x;
    const int mt  = bid % NMT;
    const int ot  = bid / NMT;
    const int oBase = ot * TO;
    const int mBase = mt * TM;

    for (int i = t; i < K_SEL; i += 256) koS[i] = koff[i];

    const int xw  = t & 31;                        // spatial lane within ry row
    const int ks  = (t >> 5) * 4;                  // this thread's 4 k's within BK

    int bxy[2];
#pragma unroll
    for (int ry = 0; ry < 2; ++ry) {
        int ryg = mt * 2 + ry;
        int n = ryg / 30, y = ryg - n * 30;
        bxy[ry] = n * CHW + y * W_IN + xw;
    }

    // A staging: per wave 4 gl_lds16 of 1KB (16 rows each), rows i*64+wave*16+..
    const unsigned short* wrowB = wT + (size_t)(oBase + wave * 16 + (lane >> 2)) * K_SEL
                                     + (lane & 3) * 8;
    unsigned short* lA = &As[(wave * 16) * 32];

    __syncthreads();                               // koS ready

    f32x4 acc[4][4] = {};
    int4  kk[2];
    float v[2][2][4];

    // prologue: prefetch x for kt=0
    kk[0] = *reinterpret_cast<const int4*>(&koS[ks]);
#pragma unroll
    for (int ry = 0; ry < 2; ++ry) {
        v[0][ry][0] = x[min(bxy[ry] + kk[0].x, X_ELEMS - 1)];
        v[0][ry][1] = x[min(bxy[ry] + kk[0].y, X_ELEMS - 1)];
        v[0][ry][2] = x[min(bxy[ry] + kk[0].z, X_ELEMS - 1)];
        v[0][ry][3] = x[min(bxy[ry] + kk[0].w, X_ELEMS - 1)];
    }

    for (int kt = 0; kt < KITER; ++kt) {
        const int p = kt & 1, q = p ^ 1;
        const int k0 = kt * 32;
#pragma unroll
        for (int i = 0; i < 4; ++i)
            gl_lds16(wrowB + (size_t)i * 64 * K_SEL + k0, lA + i * 64 * 32);

        // issue next iter's x loads early (latency overlaps pack + MFMA)
        if (kt + 1 < KITER) {
            kk[q] = *reinterpret_cast<const int4*>(&koS[k0 + 32 + ks]);
#pragma unroll
            for (int ry = 0; ry < 2; ++ry) {
                v[q][ry][0] = x[min(bxy[ry] + kk[q].x, X_ELEMS - 1)];
                v[q][ry][1] = x[min(bxy[ry] + kk[q].y, X_ELEMS - 1)];
                v[q][ry][2] = x[min(bxy[ry] + kk[q].z, X_ELEMS - 1)];
                v[q][ry][3] = x[min(bxy[ry] + kk[q].w, X_ELEMS - 1)];
            }
        }
        // commit current B-tile: packed bf16 cvt, k-contiguous ds_write_b64
#pragma unroll
        for (int ry = 0; ry < 2; ++ry) {
            __hip_bfloat162 h0 = __float22bfloat162_rn({v[p][ry][0], v[p][ry][1]});
            __hip_bfloat162 h1 = __float22bfloat162_rn({v[p][ry][2], v[p][ry][3]});
            unsigned int u0, u1;
            __builtin_memcpy(&u0, &h0, 4);
            __builtin_memcpy(&u1, &h1, 4);
            uint2 pk; pk.x = u0; pk.y = u1;
            *reinterpret_cast<uint2*>(&Bs[(ry * 32 + xw) * BSTR + ks]) = pk;
        }
        __syncthreads();                           // As (vmcnt) + Bs (lgkmcnt) visible

        bf16x8 a[4], b[4];
#pragma unroll
        for (int ms = 0; ms < 4; ++ms)
            a[ms] = *(const bf16x8*)&As[(wave * 64 + ms * 16 + lo) * 32 + quad * 8];
#pragma unroll
        for (int ns = 0; ns < 4; ++ns)
            b[ns] = *(const bf16x8*)&Bs[(ns * 16 + lo) * BSTR + quad * 8];
#pragma unroll
        for (int ms = 0; ms < 4; ++ms)
#pragma unroll
            for (int ns = 0; ns < 4; ++ns)
                acc[ms][ns] = __builtin_amdgcn_mfma_f32_16x16x32_bf16(
                    a[ms], b[ns], acc[ms][ns], 0, 0, 0);
        __syncthreads();                           // tiles consumed before next stage
    }

    // Epilogue (verified mapping): D row = o (quad*4+r), col = m (lane&15).
#pragma unroll
    for (int ns = 0; ns < 4; ++ns) {
        const int mh  = mBase + ns * 16 + lo;
        const int xwe = mh & 31;
        const int ryg = mh >> 5;
        const int n = ryg / 30, y = ryg - n * 30;
        if (xwe < OW) {
            const size_t ob = (size_t)n * (OUTC * OUT_SP) + (size_t)y * OW + xwe;
#pragma unroll
            for (int ms = 0; ms < 4; ++ms) {
                const int o0 = oBase + wave * 64 + ms * 16 + quad * 4;
#pragma unroll
                for (int r = 0; r < 4; ++r)
                    out[ob + (size_t)(o0 + r) * OUT_SP] = acc[ms][ns][r];
            }
        }
    }
}

// ---------------------------------------------------------------------------
extern "C" void kernel_launch(void* const* d_in, const int* in_sizes, int n_in,
                              void* d_out, int out_size, void* d_ws, size_t ws_size,
                              hipStream_t stream) {
    const float* x   = (const float*)d_in[0];
    const float* w   = (const float*)d_in[1];
    const int*   idx = (const int*)d_in[2];
    float*       out = (float*)d_out;

    // ws layout: koff 4608B | wT bf16 1179648B  (~1.2 MB total)
    char* ws = (char*)d_ws;
    int*            koff = (int*)ws;
    unsigned short* wT   = (unsigned short*)(ws + 4608);

    prep_kernel<<<dim3(K_SEL / 32, OUTC / 32), dim3(256), 0, stream>>>(idx, w, koff, wT);
    gemm_kernel<<<dim3(NMT * NOT), dim3(256), 0, stream>>>(wT, x, koff, out);
}

// Round 6
// 129.800 us; speedup vs baseline: 1.1118x; 1.1118x over previous
//
#include <hip/hip_runtime.h>
#include <hip/hip_bf16.h>
#include <stdint.h>

// Problem constants (fixed by reference)
#define N_IMG   16
#define C_IN    256
#define H_IN    32
#define W_IN    32
#define OH      30
#define OW      30
#define K_SEL   1152                   // C*KH*KW/2
#define OUTC    512
#define RY_TOT  (N_IMG * OH)           // 480 (n,y) rows
#define M_HAT   (RY_TOT * 32)          // 15360 = padded M (ow 30 -> 32)
#define X_ELEMS (N_IMG * C_IN * H_IN * W_IN)   // 4194304
#define OUT_SP  (OH * OW)              // 900
#define CHW     (C_IN * H_IN * W_IN)   // 262144

#define TO      128                    // o-tile (R3 shape: latency-hiding via 960 blocks)
#define TM      64                     // m-tile = 2 ry rows x 32 xw
#define NMT     (M_HAT / TM)           // 240
#define NOT     (OUTC / TO)            // 4
#define BSTR    40                     // Bs row stride (shorts): 80B rows, 16B-aligned b128
#define KITER   (K_SEL / 32)           // 36

typedef float f32x4  __attribute__((ext_vector_type(4)));
typedef short bf16x8 __attribute__((ext_vector_type(8)));   // 8 bf16 = 4 VGPRs

__device__ __forceinline__ unsigned short f2bf(float f) {   // fp32 -> bf16 RNE
    unsigned int u = __float_as_uint(f);
    u += 0x7FFFu + ((u >> 16) & 1u);
    return (unsigned short)(u >> 16);
}

// async global->LDS, 16B/lane; LDS dst wave-uniform base, HW adds lane*16.
__device__ __forceinline__ void gl_lds16(const void* g, void* lds) {
    __builtin_amdgcn_global_load_lds(
        (const __attribute__((address_space(1))) unsigned int*)g,
        (__attribute__((address_space(3))) unsigned int*)lds,
        16, 0, 0);
}

// ---------------------------------------------------------------------------
// Prep: koff decode + coalesced LDS-tile transpose w(K_SEL x OUTC fp32) ->
// wT(OUTC x K_SEL bf16). Grid (36 s-tiles, 16 o-tiles) x 256 thr.
// ---------------------------------------------------------------------------
__global__ void prep_kernel(const int* __restrict__ idx, const float* __restrict__ w,
                            int* __restrict__ koff, unsigned short* __restrict__ wT) {
    __shared__ float tile[32][33];                 // +1 pad: phase1 conflict-free
    const int bx = blockIdx.x, by = blockIdx.y, t = threadIdx.x;

    if (by == 0) {                                 // fold koff decode into first row
        int k = bx * 256 + t;
        if (k < K_SEL) {
            int v = idx[k];
            int c = v / 9, rem = v - c * 9;
            int i = rem / 3, j = rem - i * 3;
            koff[k] = c * (H_IN * W_IN) + i * W_IN + j;
        }
    }
    const int s0 = bx * 32, o0 = by * 32;
    const int oc = t & 31, sg = t >> 5;
#pragma unroll
    for (int i = 0; i < 4; ++i) {                  // coalesced 128B reads along o
        int sl = sg * 4 + i;
        tile[sl][oc] = w[(s0 + sl) * OUTC + o0 + oc];
    }
    __syncthreads();
    const int ol = t >> 3, sq = t & 7;             // write along s: coalesced
    unsigned int u0 = (unsigned int)f2bf(tile[sq * 4 + 0][ol]) |
                      ((unsigned int)f2bf(tile[sq * 4 + 1][ol]) << 16);
    unsigned int u1 = (unsigned int)f2bf(tile[sq * 4 + 2][ol]) |
                      ((unsigned int)f2bf(tile[sq * 4 + 3][ol]) << 16);
    uint2 pk; pk.x = u0; pk.y = u1;
    *reinterpret_cast<uint2*>(&wT[(size_t)(o0 + ol) * K_SEL + s0 + sq * 4]) = pk;
}

// ---------------------------------------------------------------------------
// Fused GEMM, single-barrier double-buffered K-loop.
// out[n,o,y,x] = sum_k wT[o][k] * x[n, koff[k] + y*32 + xw]
// Tile 128o x 64m, BK=32, 960 blocks (3.75/CU). Per iter kt:
//   stage As[q]<-wT(kt+1) async; pack v(kt+1)->Bs[q]; issue x loads(kt+2);
//   ds_read+8 MFMA from tiles[p]; ONE __syncthreads.
// x loads get a full MFMA section of latency cover before their drain.
// ---------------------------------------------------------------------------
__global__ __launch_bounds__(256, 4)
void gemm_kernel(const unsigned short* __restrict__ wT, const float* __restrict__ x,
                 const int* __restrict__ koff, float* __restrict__ out) {
    __shared__ __align__(16) unsigned short As[2][TO * 32];    // 2 x 8KB, k-contig rows
    __shared__ __align__(16) unsigned short Bs[2][TM * BSTR];  // 2 x 5KB, padded rows
    __shared__ __align__(16) int koS[K_SEL];

    const int t    = threadIdx.x;
    const int wave = t >> 6;
    const int lane = t & 63;
    const int quad = lane >> 4;
    const int lo   = lane & 15;

    const int bid = blockIdx.x;
    const int mt  = bid % NMT;
    const int ot  = bid / NMT;
    const int oBase = ot * TO;
    const int mBase = mt * TM;

    for (int i = t; i < K_SEL; i += 256) koS[i] = koff[i];

    const int xw = t & 31;                         // spatial lane within ry row
    const int ks = (t >> 5) * 4;                   // this thread's 4 k's within BK

    int bxy[2];
#pragma unroll
    for (int ry = 0; ry < 2; ++ry) {
        int ryg = mt * 2 + ry;
        int n = ryg / 30, y = ryg - n * 30;
        bxy[ry] = n * CHW + y * W_IN + xw;
    }

    // A staging (R3 layout): wave stages rows [wave*16,+16) and [64+wave*16,+16)
    const int lrow = lane >> 2, lks = (lane & 3) * 8;
    const unsigned short* wrow0 = wT + (size_t)(oBase + wave * 16 + lrow) * K_SEL + lks;
    const unsigned short* wrow1 = wrow0 + (size_t)64 * K_SEL;
    const int lA0 = (wave * 16) * 32;              // LDS row offsets within a buffer
    const int lA1 = (64 + wave * 16) * 32;

    __syncthreads();                               // koS ready

    f32x4 acc[2][4] = {};
    float v[2][2][4];                              // [buf][ry][4k]
    int4  kk;

    // ---- prologue: tiles[0] for kt=0, x data for kt=1 ----
    kk = *reinterpret_cast<const int4*>(&koS[ks]);
#pragma unroll
    for (int ry = 0; ry < 2; ++ry) {
        v[0][ry][0] = x[min(bxy[ry] + kk.x, X_ELEMS - 1)];
        v[0][ry][1] = x[min(bxy[ry] + kk.y, X_ELEMS - 1)];
        v[0][ry][2] = x[min(bxy[ry] + kk.z, X_ELEMS - 1)];
        v[0][ry][3] = x[min(bxy[ry] + kk.w, X_ELEMS - 1)];
    }
    gl_lds16(wrow0, &As[0][lA0]);
    gl_lds16(wrow1, &As[0][lA1]);
#pragma unroll
    for (int ry = 0; ry < 2; ++ry) {               // pack kt=0 -> Bs[0]
        __hip_bfloat162 h0 = __float22bfloat162_rn({v[0][ry][0], v[0][ry][1]});
        __hip_bfloat162 h1 = __float22bfloat162_rn({v[0][ry][2], v[0][ry][3]});
        uint2 pk;
        __builtin_memcpy(&pk.x, &h0, 4);
        __builtin_memcpy(&pk.y, &h1, 4);
        *reinterpret_cast<uint2*>(&Bs[0][(ry * 32 + xw) * BSTR + ks]) = pk;
    }
    kk = *reinterpret_cast<const int4*>(&koS[32 + ks]);
#pragma unroll
    for (int ry = 0; ry < 2; ++ry) {               // x for kt=1 -> v[1]
        v[1][ry][0] = x[min(bxy[ry] + kk.x, X_ELEMS - 1)];
        v[1][ry][1] = x[min(bxy[ry] + kk.y, X_ELEMS - 1)];
        v[1][ry][2] = x[min(bxy[ry] + kk.z, X_ELEMS - 1)];
        v[1][ry][3] = x[min(bxy[ry] + kk.w, X_ELEMS - 1)];
    }
    __syncthreads();                               // tiles[0] visible

    // ---- main loop: ONE barrier per iter ----
    for (int kt = 0; kt < KITER; ++kt) {
        const int p = kt & 1, q = p ^ 1;
        if (kt + 1 < KITER) {
            const int k1 = (kt + 1) * 32;
            gl_lds16(wrow0 + k1, &As[q][lA0]);     // stage next A async
            gl_lds16(wrow1 + k1, &As[q][lA1]);
#pragma unroll
            for (int ry = 0; ry < 2; ++ry) {       // pack next B (v[q] arrived ~1 iter ago)
                __hip_bfloat162 h0 = __float22bfloat162_rn({v[q][ry][0], v[q][ry][1]});
                __hip_bfloat162 h1 = __float22bfloat162_rn({v[q][ry][2], v[q][ry][3]});
                uint2 pk;
                __builtin_memcpy(&pk.x, &h0, 4);
                __builtin_memcpy(&pk.y, &h1, 4);
                *reinterpret_cast<uint2*>(&Bs[q][(ry * 32 + xw) * BSTR + ks]) = pk;
            }
        }
        if (kt + 2 < KITER) {                      // issue x loads 2 iters ahead
            kk = *reinterpret_cast<const int4*>(&koS[(kt + 2) * 32 + ks]);
#pragma unroll
            for (int ry = 0; ry < 2; ++ry) {
                v[p][ry][0] = x[min(bxy[ry] + kk.x, X_ELEMS - 1)];
                v[p][ry][1] = x[min(bxy[ry] + kk.y, X_ELEMS - 1)];
                v[p][ry][2] = x[min(bxy[ry] + kk.z, X_ELEMS - 1)];
                v[p][ry][3] = x[min(bxy[ry] + kk.w, X_ELEMS - 1)];
            }
        }

        bf16x8 a[2], b[4];
#pragma unroll
        for (int ms = 0; ms < 2; ++ms)
            a[ms] = *(const bf16x8*)&As[p][(wave * 32 + ms * 16 + lo) * 32 + quad * 8];
#pragma unroll
        for (int ns = 0; ns < 4; ++ns)
            b[ns] = *(const bf16x8*)&Bs[p][(ns * 16 + lo) * BSTR + quad * 8];
#pragma unroll
        for (int ms = 0; ms < 2; ++ms)
#pragma unroll
            for (int ns = 0; ns < 4; ++ns)
                acc[ms][ns] = __builtin_amdgcn_mfma_f32_16x16x32_bf16(
                    a[ms], b[ns], acc[ms][ns], 0, 0, 0);

        if (kt + 1 < KITER) __syncthreads();       // drains staging; tiles[q] ready
    }

    // Epilogue (verified mapping): D row = o (quad*4+r), col = m (lane&15).
#pragma unroll
    for (int ns = 0; ns < 4; ++ns) {
        const int mh  = mBase + ns * 16 + lo;
        const int xwe = mh & 31;
        const int ryg = mh >> 5;
        const int n = ryg / 30, y = ryg - n * 30;
        if (xwe < OW) {
            const size_t ob = (size_t)n * (OUTC * OUT_SP) + (size_t)y * OW + xwe;
#pragma unroll
            for (int ms = 0; ms < 2; ++ms) {
                const int o0 = oBase + wave * 32 + ms * 16 + quad * 4;
#pragma unroll
                for (int r = 0; r < 4; ++r)
                    out[ob + (size_t)(o0 + r) * OUT_SP] = acc[ms][ns][r];
            }
        }
    }
}

// ---------------------------------------------------------------------------
extern "C" void kernel_launch(void* const* d_in, const int* in_sizes, int n_in,
                              void* d_out, int out_size, void* d_ws, size_t ws_size,
                              hipStream_t stream) {
    const float* x   = (const float*)d_in[0];
    const float* w   = (const float*)d_in[1];
    const int*   idx = (const int*)d_in[2];
    float*       out = (float*)d_out;

    // ws layout: koff 4608B | wT bf16 1179648B  (~1.2 MB total)
    char* ws = (char*)d_ws;
    int*            koff = (int*)ws;
    unsigned short* wT   = (unsigned short*)(ws + 4608);

    prep_kernel<<<dim3(K_SEL / 32, OUTC / 32), dim3(256), 0, stream>>>(idx, w, koff, wT);
    gemm_kernel<<<dim3(NMT * NOT), dim3(256), 0, stream>>>(wT, x, koff, out);
}